// Round 5
// baseline (278.321 us; speedup 1.0000x reference)
//
#include <hip/hip_runtime.h>

typedef _Float16 f16;
typedef _Float16 f16x8 __attribute__((ext_vector_type(8)));
typedef float f32x4 __attribute__((ext_vector_type(4)));
typedef unsigned int u32;

#define NN 8192
#define FF 256
#define MASK_NEG -1.0e30f

// ---------------- K0: W^T in f16 (so K1 B-frags are contiguous) -------------
__global__ void k0_wt(const float* __restrict__ w, f16* __restrict__ wt) {
    int n = blockIdx.x;   // output column of W
    int k = threadIdx.x;  // input feature
    wt[n * FF + k] = (f16)w[k * FF + n];
}

// ---------------- K1: h = x @ W  (f16 out) ----------------------------------
__global__ __launch_bounds__(256) void k1_h(const float* __restrict__ x,
                                            const f16* __restrict__ wt,
                                            f16* __restrict__ h) {
    int tid = threadIdx.x;
    int wave = tid >> 6, lane = tid & 63, l15 = lane & 15, lg = lane >> 4;
    int rowBase = blockIdx.x * 32 + (wave & 1) * 16;
    int colBase = (wave >> 1) * 128;

    // A-frags: rows rowBase+l15, k = kk*32 + lg*8 + j (contiguous 8 f32)
    f16x8 afr[8];
    const float* xr = x + (size_t)(rowBase + l15) * FF + lg * 8;
#pragma unroll
    for (int kk = 0; kk < 8; ++kk) {
        float4 a0 = *(const float4*)(xr + kk * 32);
        float4 a1 = *(const float4*)(xr + kk * 32 + 4);
        f16x8 a;
        a[0] = (f16)a0.x; a[1] = (f16)a0.y; a[2] = (f16)a0.z; a[3] = (f16)a0.w;
        a[4] = (f16)a1.x; a[5] = (f16)a1.y; a[6] = (f16)a1.z; a[7] = (f16)a1.w;
        afr[kk] = a;
    }
#pragma unroll
    for (int cs = 0; cs < 8; ++cs) {
        int col = colBase + cs * 16 + l15;
        f32x4 acc = {0.f, 0.f, 0.f, 0.f};
        const f16* wr = wt + (size_t)col * FF + lg * 8;
#pragma unroll
        for (int kk = 0; kk < 8; ++kk) {
            f16x8 b = *(const f16x8*)(wr + kk * 32);
            acc = __builtin_amdgcn_mfma_f32_16x16x32_f16(afr[kk], b, acc, 0, 0, 0);
        }
#pragma unroll
        for (int r = 0; r < 4; ++r)
            h[(size_t)(rowBase + 4 * lg + r) * FF + col] = (f16)acc[r];
    }
}

// ---------------- K2a: partial row-max / row-sumexp + adj bit-pack ----------
// grid 512 = 128 row-blocks (64 rows) x 4 col-splits (2048 cols each)
__global__ __launch_bounds__(256) void k2a(const f16* __restrict__ h,
                                           const int* __restrict__ adj,
                                           u32* __restrict__ maskbits,
                                           float* __restrict__ pm,
                                           float* __restrict__ ps) {
    __shared__ __align__(16) f16 tile[128 * 256];  // 64 KB, XOR-swizzled rows
    int bid = blockIdx.x;
    int rb = bid >> 2;
    int split = bid & 3;
    int tid = threadIdx.x;
    int wave = tid >> 6, lane = tid & 63, l15 = lane & 15, lg = lane >> 4;
    int rowBase = rb * 64 + wave * 16;

    // A-frags register-resident for whole kernel (16 rows x K=256 per wave)
    f16x8 afr[8];
    {
        const f16* ar = h + (size_t)(rowBase + l15) * FF + lg * 8;
#pragma unroll
        for (int kk = 0; kk < 8; ++kk) afr[kk] = *(const f16x8*)(ar + kk * 32);
    }
    float m[4], s[4];
#pragma unroll
    for (int r = 0; r < 4; ++r) { m[r] = MASK_NEG; s[r] = 0.f; }

    int colStart = split * 2048;
    for (int it = 0; it < 16; ++it) {
        int c0 = colStart + it * 128;
        __syncthreads();
        // stage h[c0..c0+128) x 256k into LDS, swizzle byte^=((row&7)<<4)
#pragma unroll
        for (int i = 0; i < 16; ++i) {
            int chunk = tid + 256 * i;      // 4096 x 16B chunks
            int row = chunk >> 5;
            int kb = (chunk & 31) * 16;
            uint4 v = *(const uint4*)((const char*)(h + (size_t)(c0 + row) * FF) + kb);
            *(uint4*)((char*)tile + row * 512 + (kb ^ ((row & 7) << 4))) = v;
        }
        __syncthreads();
        unsigned long long bprev[4];
#pragma unroll
        for (int cs = 0; cs < 8; ++cs) {
            int trow = cs * 16 + l15;
            const char* tbase = (const char*)tile + trow * 512;
            int sw = (trow & 7) << 4;
            f32x4 acc = {0.f, 0.f, 0.f, 0.f};
#pragma unroll
            for (int kk = 0; kk < 8; ++kk) {
                f16x8 b = *(const f16x8*)(tbase + ((kk * 64 + lg * 16) ^ sw));
                acc = __builtin_amdgcn_mfma_f32_16x16x32_f16(afr[kk], b, acc, 0, 0, 0);
            }
            int col = c0 + cs * 16 + l15;
            const int* ap = adj + (size_t)(rowBase + 4 * lg) * NN + col;
#pragma unroll
            for (int r = 0; r < 4; ++r) {
                int av = ap[(size_t)r * NN];
                unsigned long long b = __ballot(av > 0);
                if (cs & 1) {
                    if (l15 == 0) {
                        u32 lo = (u32)((bprev[r] >> (16 * lg)) & 0xFFFFull);
                        u32 hi = (u32)((b >> (16 * lg)) & 0xFFFFull);
                        maskbits[(size_t)(rowBase + 4 * lg + r) * 256 +
                                 (c0 >> 5) + (cs >> 1)] = lo | (hi << 16);
                    }
                } else {
                    bprev[r] = b;
                }
                // online softmax; masked sentinel -1e30: any bogus exp(0)=1
                // accumulation while m==-1e30 is multiplied by exp(-1e30-v)=0
                // at the first real value -> exact.
                float v = (av > 0) ? acc[r] : MASK_NEG;
                float mn = fmaxf(m[r], v);
                s[r] = s[r] * __expf(m[r] - mn) + __expf(v - mn);
                m[r] = mn;
            }
        }
    }
    // combine across the 16 lanes (same lg group) holding disjoint column sets
#pragma unroll
    for (int off = 1; off < 16; off <<= 1) {
#pragma unroll
        for (int r = 0; r < 4; ++r) {
            float om = __shfl_xor(m[r], off);
            float os = __shfl_xor(s[r], off);
            float mn = fmaxf(m[r], om);
            s[r] = s[r] * __expf(m[r] - mn) + os * __expf(om - mn);
            m[r] = mn;
        }
    }
    if (l15 == 0) {
        int row0 = rowBase + 4 * lg;
#pragma unroll
        for (int r = 0; r < 4; ++r) {
            pm[split * NN + row0 + r] = m[r];
            ps[split * NN + row0 + r] = s[r];
        }
    }
}

// ---------------- K2r: reduce 4 partials -> final (m, 1/S) ------------------
__global__ void k2r(const float* __restrict__ pm, const float* __restrict__ ps,
                    float* __restrict__ fm, float* __restrict__ frs) {
    int row = blockIdx.x * 256 + threadIdx.x;
    float M = MASK_NEG, S = 0.f;
#pragma unroll
    for (int i = 0; i < 4; ++i) {
        float m = pm[i * NN + row];
        float s = ps[i * NN + row];
        float mn = fmaxf(M, m);
        S = S * __expf(M - mn) + s * __expf(m - mn);
        M = mn;
    }
    fm[row] = M;
    frs[row] = 1.0f / S;
}

// ---------------- K2b: recompute e, write softmax ---------------------------
// grid (64 col-blocks x 128 row-blocks)
__global__ __launch_bounds__(256) void k2b(const f16* __restrict__ h,
                                           const u32* __restrict__ maskbits,
                                           const float* __restrict__ fm,
                                           const float* __restrict__ frs,
                                           float* __restrict__ out) {
    __shared__ __align__(16) f16 tile[128 * 256];
    int cb = blockIdx.x;
    int rb = blockIdx.y;
    int tid = threadIdx.x;
    int wave = tid >> 6, lane = tid & 63, l15 = lane & 15, lg = lane >> 4;
    int rowBase = rb * 64 + wave * 16;
    int c0 = cb * 128;

#pragma unroll
    for (int i = 0; i < 16; ++i) {
        int chunk = tid + 256 * i;
        int row = chunk >> 5;
        int kb = (chunk & 31) * 16;
        uint4 v = *(const uint4*)((const char*)(h + (size_t)(c0 + row) * FF) + kb);
        *(uint4*)((char*)tile + row * 512 + (kb ^ ((row & 7) << 4))) = v;
    }
    f16x8 afr[8];
    const f16* ar = h + (size_t)(rowBase + l15) * FF + lg * 8;
#pragma unroll
    for (int kk = 0; kk < 8; ++kk) afr[kk] = *(const f16x8*)(ar + kk * 32);

    float M[4], RS[4];
#pragma unroll
    for (int r = 0; r < 4; ++r) {
        M[r]  = fm[rowBase + 4 * lg + r];
        RS[r] = frs[rowBase + 4 * lg + r];
    }
    __syncthreads();

#pragma unroll
    for (int cs = 0; cs < 8; ++cs) {
        int trow = cs * 16 + l15;
        const char* tbase = (const char*)tile + trow * 512;
        int sw = (trow & 7) << 4;
        f32x4 acc = {0.f, 0.f, 0.f, 0.f};
#pragma unroll
        for (int kk = 0; kk < 8; ++kk) {
            f16x8 b = *(const f16x8*)(tbase + ((kk * 64 + lg * 16) ^ sw));
            acc = __builtin_amdgcn_mfma_f32_16x16x32_f16(afr[kk], b, acc, 0, 0, 0);
        }
        int col = c0 + cs * 16 + l15;
        int bit = (cs & 1) * 16 + l15;
#pragma unroll
        for (int r = 0; r < 4; ++r) {
            int row = rowBase + 4 * lg + r;
            u32 mw = maskbits[(size_t)row * 256 + (c0 >> 5) + (cs >> 1)];
            float v = ((mw >> bit) & 1u) ? acc[r] : MASK_NEG;
            // masked: exp(-1e30 - M) underflows to exactly 0 (matches jax)
            out[(size_t)row * NN + col] = __expf(v - M[r]) * RS[r];
        }
    }
}

extern "C" void kernel_launch(void* const* d_in, const int* in_sizes, int n_in,
                              void* d_out, int out_size, void* d_ws, size_t ws_size,
                              hipStream_t stream) {
    const float* x   = (const float*)d_in[0];
    const int*   adj = (const int*)d_in[1];
    const float* w   = (const float*)d_in[2];
    float* out = (float*)d_out;
    char* ws = (char*)d_ws;

    // workspace layout (~12.5 MB)
    f16* h    = (f16*)(ws);                              // 4,194,304 B
    f16* wt   = (f16*)(ws + 4194304);                    //   131,072 B
    u32* mask = (u32*)(ws + 4194304 + 131072);           // 8,388,608 B
    float* pm = (float*)(ws + 4194304 + 131072 + 8388608);
    float* ps = pm + 4 * NN;
    float* fm = ps + 4 * NN;
    float* frs = fm + NN;

    k0_wt<<<dim3(256), dim3(256), 0, stream>>>(w, wt);
    k1_h <<<dim3(256), dim3(256), 0, stream>>>(x, wt, h);
    k2a  <<<dim3(512), dim3(256), 0, stream>>>(h, adj, mask, pm, ps);
    k2r  <<<dim3(32),  dim3(256), 0, stream>>>(pm, ps, fm, frs);
    k2b  <<<dim3(64, 128), dim3(256), 0, stream>>>(h, mask, fm, frs, out);
}

// Round 6
// 217.271 us; speedup vs baseline: 1.2810x; 1.2810x over previous
//
#include <hip/hip_runtime.h>

typedef _Float16 f16;
typedef _Float16 f16x8 __attribute__((ext_vector_type(8)));
typedef float f32x4 __attribute__((ext_vector_type(4)));
typedef unsigned int u32;

#define NN 8192
#define FF 256
#define MASK_NEG -1.0e30f

// async global->LDS, 16B per lane. LDS dest = wave-uniform base + lane*16.
__device__ __forceinline__ void gload_lds16(const void* gsrc, void* ldst) {
    __builtin_amdgcn_global_load_lds(
        (const __attribute__((address_space(1))) u32*)gsrc,
        (__attribute__((address_space(3))) u32*)ldst, 16, 0, 0);
}

// ---------------- K0: W^T in f16 (so K1 B-frags are contiguous) -------------
__global__ void k0_wt(const float* __restrict__ w, f16* __restrict__ wt) {
    int n = blockIdx.x;   // output column of W
    int k = threadIdx.x;  // input feature
    wt[n * FF + k] = (f16)w[k * FF + n];
}

// ---------------- K1: h = x @ W  (f16 out) ----------------------------------
__global__ __launch_bounds__(256) void k1_h(const float* __restrict__ x,
                                            const f16* __restrict__ wt,
                                            f16* __restrict__ h) {
    int tid = threadIdx.x;
    int wave = tid >> 6, lane = tid & 63, l15 = lane & 15, lg = lane >> 4;
    int rowBase = blockIdx.x * 32 + (wave & 1) * 16;
    int colBase = (wave >> 1) * 128;

    f16x8 afr[8];
    const float* xr = x + (size_t)(rowBase + l15) * FF + lg * 8;
#pragma unroll
    for (int kk = 0; kk < 8; ++kk) {
        float4 a0 = *(const float4*)(xr + kk * 32);
        float4 a1 = *(const float4*)(xr + kk * 32 + 4);
        f16x8 a;
        a[0] = (f16)a0.x; a[1] = (f16)a0.y; a[2] = (f16)a0.z; a[3] = (f16)a0.w;
        a[4] = (f16)a1.x; a[5] = (f16)a1.y; a[6] = (f16)a1.z; a[7] = (f16)a1.w;
        afr[kk] = a;
    }
#pragma unroll
    for (int cs = 0; cs < 8; ++cs) {
        int col = colBase + cs * 16 + l15;
        f32x4 acc = {0.f, 0.f, 0.f, 0.f};
        const f16* wr = wt + (size_t)col * FF + lg * 8;
#pragma unroll
        for (int kk = 0; kk < 8; ++kk) {
            f16x8 b = *(const f16x8*)(wr + kk * 32);
            acc = __builtin_amdgcn_mfma_f32_16x16x32_f16(afr[kk], b, acc, 0, 0, 0);
        }
#pragma unroll
        for (int r = 0; r < 4; ++r)
            h[(size_t)(rowBase + 4 * lg + r) * FF + col] = (f16)acc[r];
    }
}

// ---------------- K2a: fused adj-pack + partial row-max / row-sumexp --------
// grid 512 = 128 row-blocks (64 rows) x 4 col-splits (2048 cols each)
__global__ __launch_bounds__(256) void k2a(const f16* __restrict__ h,
                                           const int* __restrict__ adj,
                                           u32* __restrict__ maskbits,
                                           float* __restrict__ pm,
                                           float* __restrict__ ps) {
    __shared__ __align__(16) f16 tile[128 * 256];  // 64 KB, XOR-swizzled rows
    int bid = blockIdx.x;
    int rb = bid >> 2, split = bid & 3;
    int tid = threadIdx.x;
    int wave = tid >> 6, lane = tid & 63, l15 = lane & 15, lg = lane >> 4;
    int rowBase = rb * 64 + wave * 16;

    // A-frags register-resident (16 rows x K=256 per wave)
    f16x8 afr[8];
    {
        const f16* ar = h + (size_t)(rowBase + l15) * FF + lg * 8;
#pragma unroll
        for (int kk = 0; kk < 8; ++kk) afr[kk] = *(const f16x8*)(ar + kk * 32);
    }
    float m[4], s[4];
#pragma unroll
    for (int r = 0; r < 4; ++r) { m[r] = MASK_NEG; s[r] = 0.f; }

    int colStart = split * 2048;
    // this lane packs the mask word for (row prow, 32 cols at word-col pwc)
    int prow = rowBase + (lane >> 2);
    int pwc = lane & 3;
    const int* adjRow = adj + (size_t)prow * NN;

    int4 aj[8];
    {   // prologue: adj loads for it=0 (32 consecutive ints = this lane's word)
        const int4* ap = (const int4*)(adjRow + colStart + pwc * 32);
#pragma unroll
        for (int k = 0; k < 8; ++k) aj[k] = ap[k];
    }

    for (int it = 0; it < 16; ++it) {
        int c0 = colStart + it * 128;
        __syncthreads();  // previous tile's readers done
        // stage h[c0..c0+128) x 256 f16 -> LDS, swizzle via pre-swizzled src
#pragma unroll
        for (int i = 0; i < 16; ++i) {
            int cbase = i * 256 + wave * 64;
            int c = cbase + lane;
            int row = c >> 5;
            int kb = (c & 31) * 16;
            const char* src = (const char*)h + (size_t)(c0 + row) * 512
                              + (kb ^ ((row & 7) << 4));
            gload_lds16(src, (char*)tile + (size_t)cbase * 16);
        }
        __syncthreads();  // h tile in LDS, aj regs landed

        // pack this it's mask word; persist for k2b
        u32 word = 0;
#pragma unroll
        for (int k = 0; k < 8; ++k) {
            word |= (aj[k].x > 0 ? 1u : 0u) << (k * 4);
            word |= (aj[k].y > 0 ? 1u : 0u) << (k * 4 + 1);
            word |= (aj[k].z > 0 ? 1u : 0u) << (k * 4 + 2);
            word |= (aj[k].w > 0 ? 1u : 0u) << (k * 4 + 3);
        }
        maskbits[(size_t)prow * 256 + (c0 >> 5) + pwc] = word;

        // prefetch adj for it+1 (hidden under MFMA + softmax below)
        if (it + 1 < 16) {
            const int4* ap = (const int4*)(adjRow + c0 + 128 + pwc * 32);
#pragma unroll
            for (int k = 0; k < 8; ++k) aj[k] = ap[k];
        }

        // e-tile: acc[cs][r] for 16 rows x 128 cols
        f32x4 acc[8];
#pragma unroll
        for (int cs = 0; cs < 8; ++cs) {
            int trow = cs * 16 + l15;
            const char* tbase = (const char*)tile + trow * 512;
            int sw = (trow & 7) << 4;
            f32x4 a = {0.f, 0.f, 0.f, 0.f};
#pragma unroll
            for (int kk = 0; kk < 8; ++kk) {
                f16x8 b = *(const f16x8*)(tbase + ((kk * 64 + lg * 16) ^ sw));
                a = __builtin_amdgcn_mfma_f32_16x16x32_f16(afr[kk], b, a, 0, 0, 0);
            }
            acc[cs] = a;
        }

        // deferred per-tile softmax: one rescale per (r, it).
        // all-masked-so-far rows accumulate bogus s while m==-1e30; the
        // rescale exp(m_old - mn) = 0 at the first real value kills it.
#pragma unroll
        for (int r = 0; r < 4; ++r) {
            int srcBase = 16 * lg + 4 * r;  // lane holding (row 4lg+r, word wc)
            float vv[8];
            float tm = MASK_NEG;
#pragma unroll
            for (int wc = 0; wc < 4; ++wc) {
                u32 w = (u32)__shfl((int)word, srcBase + wc, 64);
                float v0 = ((w >> l15) & 1u) ? acc[wc * 2][r] : MASK_NEG;
                float v1 = ((w >> (16 + l15)) & 1u) ? acc[wc * 2 + 1][r] : MASK_NEG;
                vv[wc * 2] = v0;
                vv[wc * 2 + 1] = v1;
                tm = fmaxf(tm, fmaxf(v0, v1));
            }
            float mn = fmaxf(m[r], tm);
            float add = 0.f;
#pragma unroll
            for (int cs = 0; cs < 8; ++cs) add += __expf(vv[cs] - mn);
            s[r] = s[r] * __expf(m[r] - mn) + add;
            m[r] = mn;
        }
    }

    // combine across the 16 lanes (same lg group) holding disjoint column sets
#pragma unroll
    for (int off = 1; off < 16; off <<= 1) {
#pragma unroll
        for (int r = 0; r < 4; ++r) {
            float om = __shfl_xor(m[r], off);
            float os = __shfl_xor(s[r], off);
            float mn = fmaxf(m[r], om);
            s[r] = s[r] * __expf(m[r] - mn) + os * __expf(om - mn);
            m[r] = mn;
        }
    }
    if (l15 == 0) {
        int row0 = rowBase + 4 * lg;
#pragma unroll
        for (int r = 0; r < 4; ++r) {
            pm[split * NN + row0 + r] = m[r];
            ps[split * NN + row0 + r] = s[r];
        }
    }
}

// ---------------- K2r: reduce 4 partials -> final (m, 1/S) ------------------
__global__ void k2r(const float* __restrict__ pm, const float* __restrict__ ps,
                    float* __restrict__ fm, float* __restrict__ frs) {
    int row = blockIdx.x * 256 + threadIdx.x;
    float M = MASK_NEG, S = 0.f;
#pragma unroll
    for (int i = 0; i < 4; ++i) {
        float m = pm[i * NN + row];
        float s = ps[i * NN + row];
        float mn = fmaxf(M, m);
        S = S * __expf(M - mn) + s * __expf(m - mn);
        M = mn;
    }
    fm[row] = M;
    frs[row] = 1.0f / S;
}

// ---------------- K2b: recompute e, write softmax ---------------------------
// grid (64 col-blocks x 128 row-blocks)
__global__ __launch_bounds__(256) void k2b(const f16* __restrict__ h,
                                           const u32* __restrict__ maskbits,
                                           const float* __restrict__ fm,
                                           const float* __restrict__ frs,
                                           float* __restrict__ out) {
    __shared__ __align__(16) f16 tile[128 * 256];
    int cb = blockIdx.x;
    int rb = blockIdx.y;
    int tid = threadIdx.x;
    int wave = tid >> 6, lane = tid & 63, l15 = lane & 15, lg = lane >> 4;
    int rowBase = rb * 64 + wave * 16;
    int c0 = cb * 128;

    // stage h tile (pre-swizzled source -> linear LDS dest)
#pragma unroll
    for (int i = 0; i < 16; ++i) {
        int cbase = i * 256 + wave * 64;
        int c = cbase + lane;
        int row = c >> 5;
        int kb = (c & 31) * 16;
        const char* src = (const char*)h + (size_t)(c0 + row) * 512
                          + (kb ^ ((row & 7) << 4));
        gload_lds16(src, (char*)tile + (size_t)cbase * 16);
    }

    // this lane's mask word: (row rowBase+(lane>>2), word-col cb*4+(lane&3))
    u32 word = maskbits[(size_t)(rowBase + (lane >> 2)) * 256 + cb * 4 + (lane & 3)];

    f16x8 afr[8];
    const f16* ar = h + (size_t)(rowBase + l15) * FF + lg * 8;
#pragma unroll
    for (int kk = 0; kk < 8; ++kk) afr[kk] = *(const f16x8*)(ar + kk * 32);

    float M[4], RS[4];
#pragma unroll
    for (int r = 0; r < 4; ++r) {
        M[r] = fm[rowBase + 4 * lg + r];
        RS[r] = frs[rowBase + 4 * lg + r];
    }
    __syncthreads();

    f32x4 acc[8];
#pragma unroll
    for (int cs = 0; cs < 8; ++cs) {
        int trow = cs * 16 + l15;
        const char* tbase = (const char*)tile + trow * 512;
        int sw = (trow & 7) << 4;
        f32x4 a = {0.f, 0.f, 0.f, 0.f};
#pragma unroll
        for (int kk = 0; kk < 8; ++kk) {
            f16x8 b = *(const f16x8*)(tbase + ((kk * 64 + lg * 16) ^ sw));
            a = __builtin_amdgcn_mfma_f32_16x16x32_f16(afr[kk], b, a, 0, 0, 0);
        }
        acc[cs] = a;
    }

#pragma unroll
    for (int r = 0; r < 4; ++r) {
        int row = rowBase + 4 * lg + r;
        int srcBase = 16 * lg + 4 * r;
        float* orow = out + (size_t)row * NN + c0;
#pragma unroll
        for (int wc = 0; wc < 4; ++wc) {
            u32 w = (u32)__shfl((int)word, srcBase + wc, 64);
            float v0 = ((w >> l15) & 1u) ? acc[wc * 2][r] : MASK_NEG;
            float v1 = ((w >> (16 + l15)) & 1u) ? acc[wc * 2 + 1][r] : MASK_NEG;
            // masked: exp(-1e30 - M) underflows to exactly 0 (matches jax)
            orow[wc * 32 + l15] = __expf(v0 - M[r]) * RS[r];
            orow[wc * 32 + 16 + l15] = __expf(v1 - M[r]) * RS[r];
        }
    }
}

extern "C" void kernel_launch(void* const* d_in, const int* in_sizes, int n_in,
                              void* d_out, int out_size, void* d_ws, size_t ws_size,
                              hipStream_t stream) {
    const float* x   = (const float*)d_in[0];
    const int*   adj = (const int*)d_in[1];
    const float* w   = (const float*)d_in[2];
    float* out = (float*)d_out;
    char* ws = (char*)d_ws;

    // workspace layout (~12.5 MB)
    f16* h    = (f16*)(ws);                              // 4,194,304 B
    f16* wt   = (f16*)(ws + 4194304);                    //   131,072 B
    u32* mask = (u32*)(ws + 4194304 + 131072);           // 8,388,608 B
    float* pm = (float*)(ws + 4194304 + 131072 + 8388608);
    float* ps = pm + 4 * NN;
    float* fm = ps + 4 * NN;
    float* frs = fm + NN;

    k0_wt<<<dim3(256), dim3(256), 0, stream>>>(w, wt);
    k1_h <<<dim3(256), dim3(256), 0, stream>>>(x, wt, h);
    k2a  <<<dim3(512), dim3(256), 0, stream>>>(h, adj, mask, pm, ps);
    k2r  <<<dim3(32),  dim3(256), 0, stream>>>(pm, ps, fm, frs);
    k2b  <<<dim3(64, 128), dim3(256), 0, stream>>>(h, mask, fm, frs, out);
}